// Round 4
// baseline (489.766 us; speedup 1.0000x reference)
//
#include <hip/hip_runtime.h>
#include <hip/hip_cooperative_groups.h>
#include <cstddef>

namespace cg = cooperative_groups;

#define VOCAB  50000
#define INPUT  512
#define HIDDEN 1024
#define BATCH  64
#define MAXLEN 256
#define NBLK   1563   // gemv blocks == lse partials per row

typedef float  f32x4 __attribute__((ext_vector_type(4)));
typedef __bf16 bf16x8 __attribute__((ext_vector_type(8)));

__device__ __forceinline__ bf16x8 cvt8(float4 a, float4 b) {
    bf16x8 r;
    r[0] = (__bf16)a.x; r[1] = (__bf16)a.y; r[2] = (__bf16)a.z; r[3] = (__bf16)a.w;
    r[4] = (__bf16)b.x; r[5] = (__bf16)b.y; r[6] = (__bf16)b.z; r[7] = (__bf16)b.w;
    return r;
}

// 16-col GEMM tile: out[64, jt*16..+16] = A[64,K] @ W[N,K]^T + bias.
// 4 waves split K; LDS reduce. Leading sync makes back-to-back calls safe.
__device__ __forceinline__ void gemm_tile(const float* __restrict__ W,
                                          const float* __restrict__ bias,
                                          const __bf16* __restrict__ A,
                                          float* __restrict__ out,
                                          int N, int K, int jt, int tid,
                                          float (*lds)[1024]) {
    int wid = tid >> 6, lane = tid & 63;
    int j  = jt * 16 + (lane & 15);
    int kg = (lane >> 4) * 8;
    int kchunk = K >> 2;
    int kbeg = wid * kchunk, kend = kbeg + kchunk;
    const float*  wrow = W + (size_t)j * K;
    const __bf16* arow = A + (size_t)(lane & 15) * K;
    f32x4 acc[4] = {};
    for (int k0 = kbeg; k0 < kend; k0 += 32) {
        int kk = k0 + kg;
        float4 w0 = *(const float4*)(wrow + kk);
        float4 w1 = *(const float4*)(wrow + kk + 4);
        bf16x8 bw = cvt8(w0, w1);
#pragma unroll
        for (int mt = 0; mt < 4; ++mt) {
            bf16x8 av = *(const bf16x8*)(arow + (size_t)mt * 16 * K + kk);
            acc[mt] = __builtin_amdgcn_mfma_f32_16x16x32_bf16(av, bw, acc[mt], 0, 0, 0);
        }
    }
    __syncthreads();
#pragma unroll
    for (int mt = 0; mt < 4; ++mt)
#pragma unroll
        for (int r = 0; r < 4; ++r) {
            int m = mt * 16 + (lane >> 4) * 4 + r;
            lds[wid][m * 16 + (lane & 15)] = acc[mt][r];
        }
    __syncthreads();
#pragma unroll
    for (int o = tid; o < 1024; o += 256) {
        float s = lds[0][o] + lds[1][o] + lds[2][o] + lds[3][o];
        int m = o >> 4, jl = o & 15;
        out[(size_t)m * N + jt * 16 + jl] = s + bias[jt * 16 + jl];
    }
}

// Cooperative preamble: u2 -> scores -> softmax/context/pack -> GRU GEMMs -> combine
__global__ __launch_bounds__(256) void k_pre(
    const float* __restrict__ attn_W, const float* __restrict__ v,
    const float* __restrict__ enc,
    const int* __restrict__ last_output, const float* __restrict__ embedding,
    const float* __restrict__ hid,
    float* __restrict__ u2p, float* __restrict__ scores,
    __bf16* __restrict__ x_bf, __bf16* __restrict__ hid_bf, __bf16* __restrict__ y_bf,
    const float* __restrict__ W_ih, const float* __restrict__ b_ih, float* __restrict__ Gi,
    const float* __restrict__ W_hh, const float* __restrict__ b_hh, float* __restrict__ Gh,
    float* __restrict__ out_hnew)
{
    cg::grid_group grid = cg::this_grid();
    int bid = blockIdx.x, tid = threadIdx.x;
    __shared__ float lds4[4][1024];   // 16 KB
    __shared__ float a_s[256];
    __shared__ float red[256];
    __shared__ float u2s[1024];

    // ---- Phase 1: u2 partials. block = (hq<<6)|kc : 16 k-cols, 256 h-rows
    {
        int kc = bid & 63, hq = bid >> 6;
        int k = kc * 16 + (tid & 15);
        int h0 = hq * 256 + (tid >> 4) * 16;
        float acc = 0.f;
#pragma unroll
        for (int i = 0; i < 16; ++i) {
            int h = h0 + i;
            acc += v[h] * attn_W[(size_t)h * (2 * HIDDEN) + HIDDEN + k];
        }
        lds4[0][tid] = acc;           // [hg*16 + klane] == tid
        __syncthreads();
        if (tid < 16) {
            float s = 0.f;
#pragma unroll
            for (int hg = 0; hg < 16; ++hg) s += lds4[0][hg * 16 + tid];
            u2p[hq * 1024 + kc * 16 + tid] = s;
        }
    }
    __threadfence(); grid.sync();

    // ---- Phase 2: scores[b,t] = dot(enc[t,b,:], u2)
    for (int i = tid; i < 1024; i += 256)
        u2s[i] = u2p[i] + u2p[1024 + i] + u2p[2048 + i] + u2p[3072 + i];
    __syncthreads();
    {
        int wid = tid >> 6, lane = tid & 63;
        int wg = bid * 4 + wid;       // 0..1023, 16 rows each
#pragma unroll 2
        for (int r = 0; r < 16; ++r) {
            int p = wg * 16 + r;      // p = t*BATCH + b
            const float* row = enc + (size_t)p * HIDDEN;
            float acc = 0.f;
#pragma unroll
            for (int i = 0; i < 4; ++i) {
                float4 e = *(const float4*)(row + lane * 4 + i * 256);
                float4 u = *(const float4*)(&u2s[lane * 4 + i * 256]);
                acc += e.x * u.x + e.y * u.y + e.z * u.z + e.w * u.w;
            }
#pragma unroll
            for (int off = 32; off; off >>= 1) acc += __shfl_down(acc, off, 64);
            if (lane == 0) scores[(p & 63) * MAXLEN + (p >> 6)] = acc;
        }
    }
    __threadfence(); grid.sync();

    // ---- Phase 3: softmax + context + bf16 pack
    {
        int b = bid >> 2, hc = bid & 3;
        float s = scores[b * MAXLEN + tid];
        red[tid] = s; __syncthreads();
        for (int off = 128; off; off >>= 1) { if (tid < off) red[tid] = fmaxf(red[tid], red[tid + off]); __syncthreads(); }
        float m = red[0]; __syncthreads();
        float e = expf(s - m);
        red[tid] = e; __syncthreads();
        for (int off = 128; off; off >>= 1) { if (tid < off) red[tid] += red[tid + off]; __syncthreads(); }
        a_s[tid] = e * (1.f / red[0]);
        __syncthreads();
        int h = hc * 256 + tid;
        float acc = 0.f;
#pragma unroll 8
        for (int t = 0; t < MAXLEN; ++t)
            acc += a_s[t] * enc[(size_t)(t * BATCH + b) * HIDDEN + h];
        x_bf[b * 1536 + INPUT + h]  = (__bf16)acc;
        y_bf[b * 2048 + HIDDEN + h] = (__bf16)acc;
        if (tid < 128)
            x_bf[b * 1536 + hc * 128 + tid] =
                (__bf16)embedding[(size_t)last_output[b] * INPUT + hc * 128 + tid];
        hid_bf[b * HIDDEN + hc * 256 + tid] = (__bf16)hid[b * HIDDEN + hc * 256 + tid];
    }
    __threadfence(); grid.sync();

    // ---- Phase 4: GRU gate GEMMs (384 tile-jobs over 256 blocks)
    if (bid < 192) gemm_tile(W_ih, b_ih, x_bf,   Gi, 3072, 1536, bid,       tid, lds4);
    else           gemm_tile(W_hh, b_hh, hid_bf, Gh, 3072, 1024, bid - 192, tid, lds4);
    if (bid < 128) gemm_tile(W_hh, b_hh, hid_bf, Gh, 3072, 1024, bid + 64,  tid, lds4);
    __threadfence(); grid.sync();

    // ---- Phase 5: GRU combine
    {
        int idx = bid * 256 + tid;    // 65536 = 64*1024
        int b = idx >> 10, h = idx & 1023;
        const float* gi = Gi + (size_t)b * 3072;
        const float* gh = Gh + (size_t)b * 3072;
        float r  = 1.f / (1.f + expf(-(gi[h] + gh[h])));
        float z  = 1.f / (1.f + expf(-(gi[1024 + h] + gh[1024 + h])));
        float n  = tanhf(gi[2048 + h] + r * gh[2048 + h]);
        float hp = hid[b * HIDDEN + h];
        float hn = (1.f - z) * n + z * hp;
        out_hnew[b * HIDDEN + h] = hn;
        y_bf[b * 2048 + h] = (__bf16)hn;
    }
}

// Vocab projection: 1563 blocks, 2 x 16-col tiles (last block 1).
// Emits one online (max, sumexp) partial per (row, block).
__global__ __launch_bounds__(256) void k_gemv(const float* __restrict__ W,
                                              const float* __restrict__ bias,
                                              const __bf16* __restrict__ A,
                                              float* __restrict__ out,
                                              float* __restrict__ mw,
                                              float* __restrict__ sw) {
    int bid = blockIdx.x, tid = threadIdx.x;
    int wid = tid >> 6, lane = tid & 63;
    int kg = (lane >> 4) * 8;
    int kbeg = wid * 512, kend = kbeg + 512;     // K=2048 over 4 waves
    int ntiles = (bid == NBLK - 1) ? 1 : 2;
    int j0 = bid * 32 + (lane & 15);
    int jr0 = min(j0,      VOCAB - 1);
    int jr1 = min(j0 + 16, VOCAB - 1);
    const float*  wrow0 = W + (size_t)jr0 * 2048;
    const float*  wrow1 = W + (size_t)jr1 * 2048;
    const __bf16* arow  = A + (size_t)(lane & 15) * 2048;
    f32x4 acc[2][4] = {};
    for (int k0 = kbeg; k0 < kend; k0 += 32) {
        int kk = k0 + kg;
        float4 p0 = *(const float4*)(wrow0 + kk);
        float4 p1 = *(const float4*)(wrow0 + kk + 4);
        float4 q0 = *(const float4*)(wrow1 + kk);
        float4 q1 = *(const float4*)(wrow1 + kk + 4);
        bf16x8 bw0 = cvt8(p0, p1);
        bf16x8 bw1 = cvt8(q0, q1);
#pragma unroll
        for (int mt = 0; mt < 4; ++mt) {
            bf16x8 av = *(const bf16x8*)(arow + (size_t)mt * 16 * 2048 + kk);
            acc[0][mt] = __builtin_amdgcn_mfma_f32_16x16x32_bf16(av, bw0, acc[0][mt], 0, 0, 0);
            acc[1][mt] = __builtin_amdgcn_mfma_f32_16x16x32_bf16(av, bw1, acc[1][mt], 0, 0, 0);
        }
    }
    __shared__ float lds[4][1024];
    float Mreg = -INFINITY, Sreg = 0.f;
    for (int u = 0; u < ntiles; ++u) {
        if (u) __syncthreads();
#pragma unroll
        for (int mt = 0; mt < 4; ++mt)
#pragma unroll
            for (int r = 0; r < 4; ++r) {
                int m = mt * 16 + (lane >> 4) * 4 + r;
                lds[wid][m * 16 + (lane & 15)] = acc[u][mt][r];
            }
        __syncthreads();
#pragma unroll
        for (int o = tid; o < 1024; o += 256) {
            float s = lds[0][o] + lds[1][o] + lds[2][o] + lds[3][o];
            int m = o >> 4, jl = o & 15;
            int jj = bid * 32 + u * 16 + jl;
            s += bias[jj];
            out[(size_t)m * VOCAB + jj] = s;
            lds[0][o] = s;                       // each o owned by one thread
        }
        __syncthreads();
        if (tid < 64) {
            float mx = -INFINITY;
#pragma unroll
            for (int jl = 0; jl < 16; ++jl) mx = fmaxf(mx, lds[0][tid * 16 + jl]);
            float se = 0.f;
#pragma unroll
            for (int jl = 0; jl < 16; ++jl) se += expf(lds[0][tid * 16 + jl] - mx);
            float M2 = fmaxf(Mreg, mx);
            Sreg = Sreg * expf(Mreg - M2) + se * expf(mx - M2);
            Mreg = M2;
        }
    }
    if (tid < 64) {
        mw[(size_t)tid * NBLK + bid] = Mreg;
        sw[(size_t)tid * NBLK + bid] = Sreg;
    }
}

// Cooperative epilogue: lse per row, then grid-stride subtract
__global__ __launch_bounds__(256) void k_post(float* __restrict__ logits,
                                              const float* __restrict__ mw,
                                              const float* __restrict__ sw,
                                              float* __restrict__ lse) {
    cg::grid_group grid = cg::this_grid();
    int bid = blockIdx.x, tid = threadIdx.x;
    __shared__ float red[256];
    if (bid < 64) {
        const float* mrow = mw + (size_t)bid * NBLK;
        const float* srow = sw + (size_t)bid * NBLK;
        float m = -INFINITY;
        for (int i = tid; i < NBLK; i += 256) m = fmaxf(m, mrow[i]);
        red[tid] = m; __syncthreads();
        for (int off = 128; off; off >>= 1) { if (tid < off) red[tid] = fmaxf(red[tid], red[tid + off]); __syncthreads(); }
        m = red[0]; __syncthreads();
        float s = 0.f;
        for (int i = tid; i < NBLK; i += 256) s += srow[i] * expf(mrow[i] - m);
        red[tid] = s; __syncthreads();
        for (int off = 128; off; off >>= 1) { if (tid < off) red[tid] += red[tid + off]; __syncthreads(); }
        if (tid == 0) lse[bid] = m + logf(red[0]);
    }
    __threadfence(); grid.sync();
    for (int idx = bid * 256 + tid; idx < (BATCH * VOCAB) / 4; idx += 256 * 256) {
        size_t f = (size_t)idx * 4;
        float l = lse[(int)(f / VOCAB)];
        float4 x = *(float4*)(logits + f);
        x.x -= l; x.y -= l; x.z -= l; x.w -= l;
        *(float4*)(logits + f) = x;
    }
}

extern "C" void kernel_launch(void* const* d_in, const int* in_sizes, int n_in,
                              void* d_out, int out_size, void* d_ws, size_t ws_size,
                              hipStream_t stream) {
    const int*   last_output = (const int*)  d_in[0];
    const float* last_hidden = (const float*)d_in[1];
    const float* enc         = (const float*)d_in[2];
    const float* embedding   = (const float*)d_in[3];
    const float* attn_W      = (const float*)d_in[4];
    // d_in[5] = attn_b: t-independent -> cancels in softmax
    const float* v           = (const float*)d_in[6];
    const float* W_ih        = (const float*)d_in[7];
    const float* W_hh        = (const float*)d_in[8];
    const float* b_ih        = (const float*)d_in[9];
    const float* b_hh        = (const float*)d_in[10];
    const float* out_W       = (const float*)d_in[11];
    const float* out_b       = (const float*)d_in[12];

    float* out_logp = (float*)d_out;                         // [64][50000]
    float* out_hnew = (float*)d_out + (size_t)BATCH * VOCAB; // [64][1024]

    char* ws = (char*)d_ws;
    float*  u2p     = (float*) (ws + 0);          //  16 KB [4][1024]
    float*  scores  = (float*) (ws + 16384);      //  64 KB
    __bf16* x_bf    = (__bf16*)(ws + 81920);      // 192 KB [64][1536]
    __bf16* hid_bf  = (__bf16*)(ws + 278528);     // 128 KB [64][1024]
    __bf16* y_bf    = (__bf16*)(ws + 409600);     // 256 KB [64][2048]
    float*  Gi      = (float*) (ws + 671744);     // 768 KB [64][3072]
    float*  Gh      = (float*) (ws + 1458176);    // 768 KB
    float*  mw      = (float*) (ws + 2244608);    // 400 KB [64][1563]
    float*  sw      = (float*) (ws + 2644736);    // 400 KB
    float*  lse     = (float*) (ws + 3044864);    // 256 B

    void* a1[] = {(void*)&attn_W, (void*)&v, (void*)&enc, (void*)&last_output,
                  (void*)&embedding, (void*)&last_hidden, (void*)&u2p, (void*)&scores,
                  (void*)&x_bf, (void*)&hid_bf, (void*)&y_bf,
                  (void*)&W_ih, (void*)&b_ih, (void*)&Gi,
                  (void*)&W_hh, (void*)&b_hh, (void*)&Gh, (void*)&out_hnew};
    hipLaunchCooperativeKernel((void*)k_pre, dim3(256), dim3(256), a1, 0, stream);

    k_gemv<<<NBLK, 256, 0, stream>>>(out_W, out_b, y_bf, out_logp, mw, sw);

    void* a2[] = {(void*)&out_logp, (void*)&mw, (void*)&sw, (void*)&lse};
    hipLaunchCooperativeKernel((void*)k_post, dim3(256), dim3(256), a2, 0, stream);
}

// Round 5
// 214.396 us; speedup vs baseline: 2.2844x; 2.2844x over previous
//
#include <hip/hip_runtime.h>
#include <cstddef>

#define VOCAB  50000
#define INPUT  512
#define HIDDEN 1024
#define BATCH  64
#define MAXLEN 256
#define NBLK   1563   // gemv blocks == lse partials per row

typedef float  f32x4 __attribute__((ext_vector_type(4)));
typedef __bf16 bf16x8 __attribute__((ext_vector_type(8)));

__device__ __forceinline__ bf16x8 cvt8(float4 a, float4 b) {
    bf16x8 r;
    r[0] = (__bf16)a.x; r[1] = (__bf16)a.y; r[2] = (__bf16)a.z; r[3] = (__bf16)a.w;
    r[4] = (__bf16)b.x; r[5] = (__bf16)b.y; r[6] = (__bf16)b.z; r[7] = (__bf16)b.w;
    return r;
}

// u2[k] = sum_h v[h] * attn_W[h, HIDDEN+k].  16 blocks; block i owns k in [i*64,i*64+64).
__global__ void k_u2(const float* __restrict__ attn_W, const float* __restrict__ v,
                     float* __restrict__ u2) {
    int tid = threadIdx.x;
    int kk = blockIdx.x * 64 + (tid & 63);
    int hg = tid >> 6;
    float acc = 0.f;
#pragma unroll 8
    for (int h = hg * 256; h < hg * 256 + 256; ++h)
        acc += v[h] * attn_W[(size_t)h * (2 * HIDDEN) + HIDDEN + kk];
    __shared__ float red[4][64];
    red[hg][tid & 63] = acc;
    __syncthreads();
    if (tid < 64)
        u2[blockIdx.x * 64 + tid] = red[0][tid] + red[1][tid] + red[2][tid] + red[3][tid];
}

// blocks <4096: scores[b,t] = dot(enc[t,b,:], u2), one wave per (t,b).
// blocks >=4096: pack emb -> x_bf[:, :512] and last_hidden -> hid_bf (bf16).
__global__ void k_scores_pack(const float* __restrict__ enc, const float* __restrict__ u2,
                              float* __restrict__ scores,
                              const int* __restrict__ last_output,
                              const float* __restrict__ embedding,
                              const float* __restrict__ hid,
                              __bf16* __restrict__ x_bf, __bf16* __restrict__ hid_bf) {
    int bid = blockIdx.x, tid = threadIdx.x;
    if (bid < 4096) {
        int wid = tid >> 6, lane = tid & 63;
        int p = bid * 4 + wid;               // p = t*BATCH + b
        const float* row = enc + (size_t)p * HIDDEN;
        float acc = 0.f;
#pragma unroll
        for (int i = 0; i < 4; ++i) {
            float4 e = *(const float4*)(row + lane * 4 + i * 256);
            float4 u = *(const float4*)(u2  + lane * 4 + i * 256);
            acc += e.x * u.x + e.y * u.y + e.z * u.z + e.w * u.w;
        }
#pragma unroll
        for (int off = 32; off; off >>= 1) acc += __shfl_down(acc, off, 64);
        if (lane == 0) scores[(p & 63) * MAXLEN + (p >> 6)] = acc;
    } else {
        int idx = (bid - 4096) * 256 + tid;  // 98304 total
        if (idx < 64 * INPUT) {
            int b = idx >> 9, k = idx & 511;
            x_bf[b * 1536 + k] = (__bf16)embedding[(size_t)last_output[b] * INPUT + k];
        } else {
            idx -= 64 * INPUT;
            int b = idx >> 10, h = idx & 1023;
            hid_bf[b * HIDDEN + h] = (__bf16)hid[b * HIDDEN + h];
        }
    }
}

// Fused softmax + context + bf16 pack. 256 blocks: b = bid>>2, h-chunk = bid&3.
__global__ void k_ctx(const float* __restrict__ enc, const float* __restrict__ scores,
                      __bf16* __restrict__ x_bf, __bf16* __restrict__ y_bf) {
    int b = blockIdx.x >> 2, hc = blockIdx.x & 3, tid = threadIdx.x;
    __shared__ float a[256];
    __shared__ float red[256];
    float s = scores[b * MAXLEN + tid];
    red[tid] = s; __syncthreads();
    for (int off = 128; off; off >>= 1) { if (tid < off) red[tid] = fmaxf(red[tid], red[tid + off]); __syncthreads(); }
    float m = red[0]; __syncthreads();
    float e = expf(s - m);
    red[tid] = e; __syncthreads();
    for (int off = 128; off; off >>= 1) { if (tid < off) red[tid] += red[tid + off]; __syncthreads(); }
    a[tid] = e * (1.f / red[0]);
    __syncthreads();
    int h = hc * 256 + tid;
    float acc = 0.f;
#pragma unroll 8
    for (int t = 0; t < MAXLEN; ++t)
        acc += a[t] * enc[((size_t)(t * BATCH + b)) * HIDDEN + h];
    x_bf[b * 1536 + INPUT + h]   = (__bf16)acc;
    y_bf[b * 2048 + HIDDEN + h]  = (__bf16)acc;
}

// Small-M GEMM tile body: out[64, jt*16..+16] = A[64,K] @ W[N,K]^T + bias.
__device__ __forceinline__ void gemm_tile(const float* __restrict__ W,
                                          const float* __restrict__ bias,
                                          const __bf16* __restrict__ A,
                                          float* __restrict__ out,
                                          int N, int K, int jt, int tid) {
    int wid = tid >> 6, lane = tid & 63;
    int j  = jt * 16 + (lane & 15);
    int kg = (lane >> 4) * 8;
    int kchunk = K >> 2;
    int kbeg = wid * kchunk, kend = kbeg + kchunk;
    const float*  wrow = W + (size_t)j * K;
    const __bf16* arow = A + (size_t)(lane & 15) * K;
    f32x4 acc[4] = {};
    for (int k0 = kbeg; k0 < kend; k0 += 32) {
        int kk = k0 + kg;
        float4 w0 = *(const float4*)(wrow + kk);
        float4 w1 = *(const float4*)(wrow + kk + 4);
        bf16x8 bw = cvt8(w0, w1);
#pragma unroll
        for (int mt = 0; mt < 4; ++mt) {
            bf16x8 av = *(const bf16x8*)(arow + (size_t)mt * 16 * K + kk);
            acc[mt] = __builtin_amdgcn_mfma_f32_16x16x32_bf16(av, bw, acc[mt], 0, 0, 0);
        }
    }
    __shared__ float lds[4][1024];
#pragma unroll
    for (int mt = 0; mt < 4; ++mt)
#pragma unroll
        for (int r = 0; r < 4; ++r) {
            int m = mt * 16 + (lane >> 4) * 4 + r;
            lds[wid][m * 16 + (lane & 15)] = acc[mt][r];
        }
    __syncthreads();
#pragma unroll
    for (int o = tid; o < 1024; o += 256) {
        float s = lds[0][o] + lds[1][o] + lds[2][o] + lds[3][o];
        int m = o >> 4, jl = o & 15;
        out[(size_t)m * N + jt * 16 + jl] = s + bias[jt * 16 + jl];
    }
}

// GRU gate GEMMs, one dispatch: blocks 0..191 -> Gi (K=1536), 192..383 -> Gh (K=1024)
__global__ __launch_bounds__(256) void k_gemm_gru(const float* __restrict__ W_ih,
                                                  const float* __restrict__ b_ih,
                                                  const __bf16* __restrict__ x_bf,
                                                  float* __restrict__ Gi,
                                                  const float* __restrict__ W_hh,
                                                  const float* __restrict__ b_hh,
                                                  const __bf16* __restrict__ hid_bf,
                                                  float* __restrict__ Gh) {
    int bid = blockIdx.x, tid = threadIdx.x;
    if (bid < 192) gemm_tile(W_ih, b_ih, x_bf,  Gi, 3072, 1536, bid,       tid);
    else           gemm_tile(W_hh, b_hh, hid_bf, Gh, 3072, 1024, bid - 192, tid);
}

// GRU combine: h_new = (1-z)*n + z*h_prev
__global__ void k_combine(const float* __restrict__ Gi, const float* __restrict__ Gh,
                          const float* __restrict__ hid, float* __restrict__ hnew_out,
                          __bf16* __restrict__ y_bf) {
    int idx = blockIdx.x * 256 + threadIdx.x;   // 64*1024
    int b = idx >> 10, h = idx & 1023;
    const float* gi = Gi + (size_t)b * 3072;
    const float* gh = Gh + (size_t)b * 3072;
    float r  = 1.f / (1.f + expf(-(gi[h] + gh[h])));
    float z  = 1.f / (1.f + expf(-(gi[1024 + h] + gh[1024 + h])));
    float n  = tanhf(gi[2048 + h] + r * gh[2048 + h]);
    float hp = hid[b * HIDDEN + h];
    float hn = (1.f - z) * n + z * hp;
    hnew_out[b * HIDDEN + h] = hn;
    y_bf[b * 2048 + h] = (__bf16)hn;
}

// Vocab projection: 1563 blocks, 2 x 16-col tiles (last block 1).
// Emits one online (max, sumexp) partial per (row, block).
__global__ __launch_bounds__(256) void k_gemv(const float* __restrict__ W,
                                              const float* __restrict__ bias,
                                              const __bf16* __restrict__ A,
                                              float* __restrict__ out,
                                              float* __restrict__ mw,
                                              float* __restrict__ sw) {
    int bid = blockIdx.x, tid = threadIdx.x;
    int wid = tid >> 6, lane = tid & 63;
    int kg = (lane >> 4) * 8;
    int kbeg = wid * 512, kend = kbeg + 512;     // K=2048 over 4 waves
    int ntiles = (bid == NBLK - 1) ? 1 : 2;
    int j0 = bid * 32 + (lane & 15);
    int jr0 = min(j0,      VOCAB - 1);
    int jr1 = min(j0 + 16, VOCAB - 1);
    const float*  wrow0 = W + (size_t)jr0 * 2048;
    const float*  wrow1 = W + (size_t)jr1 * 2048;
    const __bf16* arow  = A + (size_t)(lane & 15) * 2048;
    f32x4 acc[2][4] = {};
    for (int k0 = kbeg; k0 < kend; k0 += 32) {
        int kk = k0 + kg;
        float4 p0 = *(const float4*)(wrow0 + kk);
        float4 p1 = *(const float4*)(wrow0 + kk + 4);
        float4 q0 = *(const float4*)(wrow1 + kk);
        float4 q1 = *(const float4*)(wrow1 + kk + 4);
        bf16x8 bw0 = cvt8(p0, p1);
        bf16x8 bw1 = cvt8(q0, q1);
#pragma unroll
        for (int mt = 0; mt < 4; ++mt) {
            bf16x8 av = *(const bf16x8*)(arow + (size_t)mt * 16 * 2048 + kk);
            acc[0][mt] = __builtin_amdgcn_mfma_f32_16x16x32_bf16(av, bw0, acc[0][mt], 0, 0, 0);
            acc[1][mt] = __builtin_amdgcn_mfma_f32_16x16x32_bf16(av, bw1, acc[1][mt], 0, 0, 0);
        }
    }
    __shared__ float lds[4][1024];
    float Mreg = -INFINITY, Sreg = 0.f;
    for (int u = 0; u < ntiles; ++u) {
        if (u) __syncthreads();
#pragma unroll
        for (int mt = 0; mt < 4; ++mt)
#pragma unroll
            for (int r = 0; r < 4; ++r) {
                int m = mt * 16 + (lane >> 4) * 4 + r;
                lds[wid][m * 16 + (lane & 15)] = acc[u][mt][r];
            }
        __syncthreads();
#pragma unroll
        for (int o = tid; o < 1024; o += 256) {
            float s = lds[0][o] + lds[1][o] + lds[2][o] + lds[3][o];
            int m = o >> 4, jl = o & 15;
            int jj = bid * 32 + u * 16 + jl;
            s += bias[jj];
            out[(size_t)m * VOCAB + jj] = s;
            lds[0][o] = s;                       // each o owned by one thread
        }
        __syncthreads();
        if (tid < 64) {
            float mx = -INFINITY;
#pragma unroll
            for (int jl = 0; jl < 16; ++jl) mx = fmaxf(mx, lds[0][tid * 16 + jl]);
            float se = 0.f;
#pragma unroll
            for (int jl = 0; jl < 16; ++jl) se += expf(lds[0][tid * 16 + jl] - mx);
            float M2 = fmaxf(Mreg, mx);
            Sreg = Sreg * expf(Mreg - M2) + se * expf(mx - M2);
            Mreg = M2;
        }
    }
    if (tid < 64) {
        mw[(size_t)tid * NBLK + bid] = Mreg;
        sw[(size_t)tid * NBLK + bid] = Sreg;
    }
}

// Fused lse-combine + subtract. 832 blocks = 64 rows x 13 chunks of 4096.
// Each block redundantly reduces its row's 1563 partials (6.25 KB, L2-hot),
// then subtracts lse over its aligned chunk.
__global__ __launch_bounds__(256) void k_lse_fused(float* __restrict__ logits,
                                                   const float* __restrict__ mw,
                                                   const float* __restrict__ sw) {
    int bid = blockIdx.x, tid = threadIdx.x;
    int b = bid / 13, c = bid % 13;
    const float* mrow = mw + (size_t)b * NBLK;
    const float* srow = sw + (size_t)b * NBLK;
    __shared__ float red[256];
    float m = -INFINITY;
    for (int i = tid; i < NBLK; i += 256) m = fmaxf(m, mrow[i]);
    red[tid] = m; __syncthreads();
    for (int off = 128; off; off >>= 1) { if (tid < off) red[tid] = fmaxf(red[tid], red[tid + off]); __syncthreads(); }
    m = red[0]; __syncthreads();
    float s = 0.f;
    for (int i = tid; i < NBLK; i += 256) s += srow[i] * expf(mrow[i] - m);
    red[tid] = s; __syncthreads();
    for (int off = 128; off; off >>= 1) { if (tid < off) red[tid] += red[tid + off]; __syncthreads(); }
    float lse = m + logf(red[0]);
    int base = c * 4096;
    int len  = min(4096, VOCAB - base);
    float* row = logits + (size_t)b * VOCAB + base;
    for (int i = tid * 4; i < len; i += 1024) {
        float4 x = *(float4*)(row + i);
        x.x -= lse; x.y -= lse; x.z -= lse; x.w -= lse;
        *(float4*)(row + i) = x;
    }
}

extern "C" void kernel_launch(void* const* d_in, const int* in_sizes, int n_in,
                              void* d_out, int out_size, void* d_ws, size_t ws_size,
                              hipStream_t stream) {
    const int*   last_output = (const int*)  d_in[0];
    const float* last_hidden = (const float*)d_in[1];
    const float* enc         = (const float*)d_in[2];
    const float* embedding   = (const float*)d_in[3];
    const float* attn_W      = (const float*)d_in[4];
    // d_in[5] = attn_b: t-independent -> cancels in softmax
    const float* v           = (const float*)d_in[6];
    const float* W_ih        = (const float*)d_in[7];
    const float* W_hh        = (const float*)d_in[8];
    const float* b_ih        = (const float*)d_in[9];
    const float* b_hh        = (const float*)d_in[10];
    const float* out_W       = (const float*)d_in[11];
    const float* out_b       = (const float*)d_in[12];

    float* out_logp = (float*)d_out;                         // [64][50000]
    float* out_hnew = (float*)d_out + (size_t)BATCH * VOCAB; // [64][1024]

    char* ws = (char*)d_ws;
    float*  u2      = (float*) (ws + 0);          //   4 KB
    float*  scores  = (float*) (ws + 4096);       //  64 KB
    __bf16* x_bf    = (__bf16*)(ws + 69632);      // 192 KB [64][1536]
    __bf16* hid_bf  = (__bf16*)(ws + 266240);     // 128 KB [64][1024]
    __bf16* y_bf    = (__bf16*)(ws + 397312);     // 256 KB [64][2048]
    float*  Gi      = (float*) (ws + 659456);     // 768 KB [64][3072]
    float*  Gh      = (float*) (ws + 1445888);    // 768 KB
    float*  mw      = (float*) (ws + 2232320);    // 400 KB [64][1563]
    float*  sw      = (float*) (ws + 2636800);    // 400 KB

    k_u2          <<<16,   256, 0, stream>>>(attn_W, v, u2);
    k_scores_pack <<<4480, 256, 0, stream>>>(enc, u2, scores, last_output, embedding,
                                             last_hidden, x_bf, hid_bf);
    k_ctx         <<<256,  256, 0, stream>>>(enc, scores, x_bf, y_bf);
    k_gemm_gru    <<<384,  256, 0, stream>>>(W_ih, b_ih, x_bf, Gi, W_hh, b_hh, hid_bf, Gh);
    k_combine     <<<256,  256, 0, stream>>>(Gi, Gh, last_hidden, out_hnew, y_bf);
    k_gemv        <<<NBLK, 256, 0, stream>>>(out_W, out_b, y_bf, out_logp, mw, sw);
    k_lse_fused   <<<832,  256, 0, stream>>>(out_logp, mw, sw);
}